// Round 1
// baseline (758.507 us; speedup 1.0000x reference)
//
#include <hip/hip_runtime.h>
#include <hip/hip_bf16.h>
#include <cstdint>
#include <cstddef>

#define BB 16
#define NN 128
#define MM 1024
#define DN 512
#define DE 256
#define WN 128
#define WE 128
#define PP 512
#define HIDW 256
#define CIW 512

// ---------------------------------------------------------------- K1:
// Y = (X*nmask) @ Wn, Xp = (X*nmask) @ Wn2   per (b, 16-row tile)
__global__ __launch_bounds__(256) void k1_node_proj(
    const float* __restrict__ nf, const float* __restrict__ Wn,
    const float* __restrict__ Wn2, const int* __restrict__ num_obj,
    float* __restrict__ Y, float* __restrict__ Xp)
{
    __shared__ float Xs[16 * 513];
    int b  = blockIdx.x >> 3;
    int i0 = (blockIdx.x & 7) * 16;
    int s  = num_obj[b];
    int t  = threadIdx.x;
    for (int rr = 0; rr < 16; ++rr) {
        int i = i0 + rr;
        const float* row = nf + (size_t)(b * NN + i) * DN;
        float v0 = (i < s) ? row[t]       : 0.0f;
        float v1 = (i < s) ? row[t + 256] : 0.0f;
        Xs[rr * 513 + t]       = v0;
        Xs[rr * 513 + t + 256] = v1;
    }
    __syncthreads();
    int c  = t & 127;
    int rb = (t >> 7) * 8;
    float a1[8], a2[8];
    #pragma unroll
    for (int r = 0; r < 8; ++r) { a1[r] = 0.f; a2[r] = 0.f; }
    for (int k = 0; k < DN; ++k) {
        float w1 = Wn[k * WN + c];
        float w2 = Wn2[k * WN + c];
        #pragma unroll
        for (int r = 0; r < 8; ++r) {
            float xv = Xs[(rb + r) * 513 + k];
            a1[r] += xv * w1;
            a2[r] += xv * w2;
        }
    }
    #pragma unroll
    for (int r = 0; r < 8; ++r) {
        int i = i0 + rb + r;
        Y [(b * NN + i) * WN + c] = a1[r];
        Xp[(b * NN + i) * WN + c] = a2[r];
    }
}

// ---------------------------------------------------------------- K2:
// h = relu(A @ Y) (masked), writes node_emb[..., :128]; zeroes agg half.
__global__ __launch_bounds__(256) void k2_gcn_node(
    const float* __restrict__ adj, const int* __restrict__ num_obj,
    const float* __restrict__ Y, float* __restrict__ node_emb)
{
    __shared__ float As[16 * 129];
    int b  = blockIdx.x >> 3;
    int i0 = (blockIdx.x & 7) * 16;
    int s  = num_obj[b];
    int t  = threadIdx.x;
    if (t < 128) {
        for (int rr = 0; rr < 16; ++rr) {
            int i = i0 + rr;
            float v = 0.f;
            if (i < s) {
                v = adj[(size_t)(b * NN + i) * NN + t] * ((t < s) ? 1.f : 0.f);
                if (t == i) v += 1.f;
            }
            As[rr * 129 + t] = v;
        }
    }
    __syncthreads();
    int c  = t & 127;
    int rb = (t >> 7) * 8;
    float acc[8];
    #pragma unroll
    for (int r = 0; r < 8; ++r) acc[r] = 0.f;
    for (int j = 0; j < NN; ++j) {
        float yv = Y[(b * NN + j) * WN + c];
        #pragma unroll
        for (int r = 0; r < 8; ++r) acc[r] += As[(rb + r) * 129 + j] * yv;
    }
    #pragma unroll
    for (int r = 0; r < 8; ++r) {
        int i = i0 + rb + r;
        node_emb[(b * NN + i) * 256 + c]       = fmaxf(acc[r], 0.f);
        node_emb[(b * NN + i) * 256 + 128 + c] = 0.f;   // agg half zero-init
    }
}

// ---------------------------------------------------------------- K3:
// G1 = (Eg * emask) @ We,  Eg gathered from edge_features at (src,dst)
__global__ __launch_bounds__(256) void k3_edge_proj(
    const float* __restrict__ ef, const float* __restrict__ We,
    const int* __restrict__ eidx, const int* __restrict__ num_edges,
    float* __restrict__ G1)
{
    __shared__ float Es[16 * 257];
    int b  = blockIdx.x >> 6;
    int m0 = (blockIdx.x & 63) * 16;
    int se = num_edges[b];
    int t  = threadIdx.x;
    for (int rr = 0; rr < 16; ++rr) {
        int m = m0 + rr;
        float v = 0.f;
        if (m < se) {
            int src = eidx[b * 2 * MM + m];
            int dst = eidx[b * 2 * MM + MM + m];
            v = ef[((size_t)(b * NN + src) * NN + dst) * DE + t];
        }
        Es[rr * 257 + t] = v;
    }
    __syncthreads();
    int c  = t & 127;
    int rb = (t >> 7) * 8;
    float acc[8];
    #pragma unroll
    for (int r = 0; r < 8; ++r) acc[r] = 0.f;
    for (int k = 0; k < DE; ++k) {
        float wv = We[k * WE + c];
        #pragma unroll
        for (int r = 0; r < 8; ++r) acc[r] += Es[(rb + r) * 257 + k] * wv;
    }
    #pragma unroll
    for (int r = 0; r < 8; ++r)
        G1[(size_t)(b * MM + m0 + rb + r) * WE + c] = acc[r];
}

// ---------------------------------------------------------------- K4:
// g[m] = relu(G1[m] + sum_{j: L[m,j]!=0} L[m,j]*G1[j]); scatter-add to agg.
__global__ __launch_bounds__(128) void k4_line_gcn(
    const float* __restrict__ la, const float* __restrict__ G1,
    const int* __restrict__ eidx, const int* __restrict__ num_edges,
    float* __restrict__ node_emb)
{
    int b = blockIdx.x >> 10;
    int m = blockIdx.x & 1023;
    int se = num_edges[b];
    if (m >= se) return;            // whole block exits uniformly
    __shared__ int   cnt;
    __shared__ int   idxs[MM];
    __shared__ float vals[MM];
    int t = threadIdx.x;
    if (t == 0) cnt = 0;
    __syncthreads();
    const float* larow = la + ((size_t)b * MM + m) * MM;
    for (int it = 0; it < 8; ++it) {
        int j = it * 128 + t;
        float v = larow[j];
        if (v != 0.f) {
            int pos = atomicAdd(&cnt, 1);
            idxs[pos] = j;
            vals[pos] = v;
        }
    }
    __syncthreads();
    int n = cnt;
    const float* g1b = G1 + (size_t)b * MM * WE;
    float acc = g1b[m * WE + t];           // diagonal eye*emask term
    for (int p = 0; p < n; ++p)
        acc += vals[p] * g1b[idxs[p] * WE + t];
    float g = fmaxf(acc, 0.f);
    int src = eidx[b * 2 * MM + m];
    atomicAdd(&node_emb[(b * NN + src) * 256 + 128 + t], g);
}

// ---------------------------------------------------------------- K5a:
// build ci = [emb0+emb1 (256) | relu(Xp0+Xp1) (128) | relu(ef_pair@We2) (128)]
__global__ __launch_bounds__(256) void k5a_build_ci(
    const float* __restrict__ node_emb, const float* __restrict__ Xp,
    const float* __restrict__ ef, const float* __restrict__ We2,
    const int* __restrict__ opairs, const int* __restrict__ num_obj,
    float* __restrict__ ci)
{
    __shared__ float efs[16 * 257];
    __shared__ int   pi0[16], pi1[16];
    __shared__ float nm0[16], nm1[16];
    int b     = blockIdx.x >> 5;
    int pbase = (blockIdx.x & 31) * 16;
    int t     = threadIdx.x;
    int s     = num_obj[b];
    if (t < 16) {
        int p  = pbase + t;
        int i0 = opairs[(b * PP + p) * 2];
        int i1 = opairs[(b * PP + p) * 2 + 1];
        pi0[t] = i0; pi1[t] = i1;
        nm0[t] = (i0 < s) ? 1.f : 0.f;
        nm1[t] = (i1 < s) ? 1.f : 0.f;
    }
    __syncthreads();
    for (int pp = 0; pp < 16; ++pp) {
        int i0 = pi0[pp], i1 = pi1[pp];
        int p  = pbase + pp;
        float* cirow = ci + (size_t)(b * PP + p) * CIW;
        efs[pp * 257 + t] = ef[((size_t)(b * NN + i0) * NN + i1) * DE + t];
        // emb0+emb1: h half already masked; apply nmask only on agg half
        float m0f = (t < 128) ? 1.f : nm0[pp];
        float m1f = (t < 128) ? 1.f : nm1[pp];
        float v = node_emb[(b * NN + i0) * 256 + t] * m0f
                + node_emb[(b * NN + i1) * 256 + t] * m1f;
        cirow[t] = v;
        if (t < 128) {
            float pm = Xp[(b * NN + i0) * WN + t] + Xp[(b * NN + i1) * WN + t];
            cirow[256 + t] = fmaxf(pm, 0.f);
        }
    }
    __syncthreads();
    int c   = t & 127;
    int ppb = (t >> 7) * 8;
    float acc[8];
    #pragma unroll
    for (int r = 0; r < 8; ++r) acc[r] = 0.f;
    for (int k = 0; k < DE; ++k) {
        float wv = We2[k * WE + c];
        #pragma unroll
        for (int r = 0; r < 8; ++r) acc[r] += efs[(ppb + r) * 257 + k] * wv;
    }
    #pragma unroll
    for (int r = 0; r < 8; ++r) {
        int p = pbase + ppb + r;
        ci[(size_t)(b * PP + p) * CIW + 384 + c] = fmaxf(acc[r], 0.f);
    }
}

// ---------------------------------------------------------------- K5b:
// hid = relu(ci @ W1 + b1)   (8192x512)@(512x256), 64x64 tile, 4x4/thread
__global__ __launch_bounds__(256) void k5b_mlp1(
    const float* __restrict__ Aci, const float* __restrict__ W1,
    const float* __restrict__ b1, float* __restrict__ hid)
{
    __shared__ float As[64 * 17];
    __shared__ float Bs[16 * 65];
    int row0 = blockIdx.y * 64;
    int col0 = blockIdx.x * 64;
    int t  = threadIdx.x;
    int tx = t & 15, ty = t >> 4;
    float acc[4][4];
    #pragma unroll
    for (int r = 0; r < 4; ++r)
        #pragma unroll
        for (int cq = 0; cq < 4; ++cq) acc[r][cq] = 0.f;
    for (int k0 = 0; k0 < CIW; k0 += 16) {
        #pragma unroll
        for (int q = 0; q < 4; ++q) {
            int idx = t + 256 * q;
            int r  = idx >> 4, kk = idx & 15;
            As[r * 17 + kk] = Aci[(size_t)(row0 + r) * CIW + k0 + kk];
            int kb = idx >> 6, cc = idx & 63;
            Bs[kb * 65 + cc] = W1[(k0 + kb) * HIDW + col0 + cc];
        }
        __syncthreads();
        #pragma unroll
        for (int kk = 0; kk < 16; ++kk) {
            float av[4], bv[4];
            #pragma unroll
            for (int r = 0; r < 4; ++r)  av[r]  = As[(ty * 4 + r) * 17 + kk];
            #pragma unroll
            for (int cq = 0; cq < 4; ++cq) bv[cq] = Bs[kk * 65 + tx * 4 + cq];
            #pragma unroll
            for (int r = 0; r < 4; ++r)
                #pragma unroll
                for (int cq = 0; cq < 4; ++cq) acc[r][cq] += av[r] * bv[cq];
        }
        __syncthreads();
    }
    #pragma unroll
    for (int r = 0; r < 4; ++r)
        #pragma unroll
        for (int cq = 0; cq < 4; ++cq) {
            int row = row0 + ty * 4 + r;
            int col = col0 + tx * 4 + cq;
            hid[(size_t)row * HIDW + col] = fmaxf(acc[r][cq] + b1[col], 0.f);
        }
}

// ---------------------------------------------------------------- K5c:
// out = hid @ W2 + b2    (8 pairs/block, 32 output slots each)
__global__ __launch_bounds__(256) void k5c_mlp2(
    const float* __restrict__ hid, const float* __restrict__ W2,
    const float* __restrict__ b2, float* __restrict__ outp, int outw)
{
    int t  = threadIdx.x;
    int pg = blockIdx.x * 8 + (t >> 5);
    int o  = t & 31;
    if (o >= outw) return;
    float acc = b2[o];
    const float* hr = hid + (size_t)pg * HIDW;
    for (int k = 0; k < HIDW; ++k) acc += hr[k] * W2[k * outw + o];
    outp[(size_t)pg * outw + o] = acc;
}

// ----------------------------------------------------------------
extern "C" void kernel_launch(void* const* d_in, const int* in_sizes, int n_in,
                              void* d_out, int out_size, void* d_ws, size_t ws_size,
                              hipStream_t stream) {
    const float* nf    = (const float*)d_in[0];
    const float* ef    = (const float*)d_in[1];
    const float* adj   = (const float*)d_in[2];
    const float* la    = (const float*)d_in[3];
    const int*   eidx  = (const int*)d_in[4];
    const int*   opair = (const int*)d_in[5];
    const int*   nobj  = (const int*)d_in[6];
    const int*   nedg  = (const int*)d_in[7];
    const float* Wn    = (const float*)d_in[8];
    const float* We    = (const float*)d_in[9];
    const float* Wn2   = (const float*)d_in[10];
    const float* We2   = (const float*)d_in[11];
    const float* scrW1 = (const float*)d_in[12];
    const float* scrb1 = (const float*)d_in[13];
    const float* scrW2 = (const float*)d_in[14];
    const float* scrb2 = (const float*)d_in[15];
    const float* lrW1  = (const float*)d_in[16];
    const float* lrb1  = (const float*)d_in[17];
    const float* lrW2  = (const float*)d_in[18];
    const float* lrb2  = (const float*)d_in[19];
    const float* mrW1  = (const float*)d_in[20];
    const float* mrb1  = (const float*)d_in[21];
    const float* mrW2  = (const float*)d_in[22];
    const float* mrb2  = (const float*)d_in[23];

    float* ws       = (float*)d_ws;
    float* Y        = ws;                       // 16*128*128      = 262144
    float* Xp       = Y + 262144;               // 262144
    float* node_emb = Xp + 262144;              // 16*128*256      = 524288
    float* G1       = node_emb + 524288;        // 16*1024*128     = 2097152
    float* ci       = G1 + 2097152;             // 8192*512        = 4194304
    float* hid      = ci + 4194304;             // 8192*256        = 2097152
    // total = 9,437,184 floats = 36 MB

    k1_node_proj<<<BB * (NN / 16), 256, 0, stream>>>(nf, Wn, Wn2, nobj, Y, Xp);
    k2_gcn_node <<<BB * (NN / 16), 256, 0, stream>>>(adj, nobj, Y, node_emb);
    k3_edge_proj<<<BB * (MM / 16), 256, 0, stream>>>(ef, We, eidx, nedg, G1);
    k4_line_gcn <<<BB * MM, 128, 0, stream>>>(la, G1, eidx, nedg, node_emb);
    k5a_build_ci<<<BB * (PP / 16), 256, 0, stream>>>(node_emb, Xp, ef, We2,
                                                     opair, nobj, ci);
    float* outp = (float*)d_out;
    const float* hW1[3] = {lrW1, scrW1, mrW1};
    const float* hb1[3] = {lrb1, scrb1, mrb1};
    const float* hW2[3] = {lrW2, scrW2, mrW2};
    const float* hb2[3] = {lrb2, scrb2, mrb2};
    const int    how[3] = {9, 6, 17};
    float*       hout[3] = {outp, outp + 8192 * 9, outp + 8192 * (9 + 6)};
    for (int h = 0; h < 3; ++h) {
        k5b_mlp1<<<dim3(4, 128), 256, 0, stream>>>(ci, hW1[h], hb1[h], hid);
        k5c_mlp2<<<8192 / 8, 256, 0, stream>>>(hid, hW2[h], hb2[h], hout[h], how[h]);
    }
}

// Round 2
// 557.215 us; speedup vs baseline: 1.3612x; 1.3612x over previous
//
#include <hip/hip_runtime.h>
#include <hip/hip_bf16.h>
#include <cstdint>
#include <cstddef>

#define BB 16
#define NN 128
#define MM 1024
#define DN 512
#define DE 256
#define WN 128
#define WE 128
#define PP 512
#define HIDW 256
#define CIW 512

typedef __attribute__((ext_vector_type(8))) short s16x8;
typedef __attribute__((ext_vector_type(4))) float f32x4;

__device__ __forceinline__ float bf2f(unsigned short u) {
    unsigned int x = ((unsigned int)u) << 16;
    union { unsigned int i; float f; } c; c.i = x; return c.f;
}

// ---------------------------------------------------------------- K0:
// prep: W1t[768][512] = bf16(W1cat^T), b1cat[768]
__global__ __launch_bounds__(256) void k0_prep(
    const float* __restrict__ lrW1, const float* __restrict__ scrW1,
    const float* __restrict__ mrW1,
    const float* __restrict__ lrb1, const float* __restrict__ scrb1,
    const float* __restrict__ mrb1,
    __hip_bfloat16* __restrict__ W1t, float* __restrict__ b1cat)
{
    int blk = blockIdx.x;
    int t = threadIdx.x;
    if (blk < 768) {
        int h = blk >> 8, n = blk & 255;
        const float* W = (h == 0) ? lrW1 : (h == 1) ? scrW1 : mrW1;
        W1t[(size_t)blk * 512 + t]       = __float2bfloat16(W[t * 256 + n]);
        W1t[(size_t)blk * 512 + t + 256] = __float2bfloat16(W[(t + 256) * 256 + n]);
    } else {
        b1cat[t]       = lrb1[t];
        b1cat[256 + t] = scrb1[t];
        b1cat[512 + t] = mrb1[t];
    }
}

// ---------------------------------------------------------------- K1:
// Y = (X*nmask) @ Wn, Xp = (X*nmask) @ Wn2.  Column-split x2 for occupancy.
__global__ __launch_bounds__(256) void k1_node_proj(
    const float* __restrict__ nf, const float* __restrict__ Wn,
    const float* __restrict__ Wn2, const int* __restrict__ num_obj,
    float* __restrict__ Y, float* __restrict__ Xp)
{
    __shared__ float Xs[16 * 513];
    int b  = blockIdx.x >> 4;
    int i0 = ((blockIdx.x >> 1) & 7) * 16;
    int ch = blockIdx.x & 1;
    int s  = num_obj[b];
    int t  = threadIdx.x;
    for (int rr = 0; rr < 16; ++rr) {
        int i = i0 + rr;
        const float* row = nf + (size_t)(b * NN + i) * DN;
        Xs[rr * 513 + t]       = (i < s) ? row[t]       : 0.f;
        Xs[rr * 513 + t + 256] = (i < s) ? row[t + 256] : 0.f;
    }
    __syncthreads();
    int c  = ch * 64 + (t & 63);
    int rb = (t >> 6) * 4;
    float a1[4] = {0.f,0.f,0.f,0.f}, a2[4] = {0.f,0.f,0.f,0.f};
    for (int k = 0; k < DN; ++k) {
        float w1 = Wn[k * WN + c];
        float w2 = Wn2[k * WN + c];
        #pragma unroll
        for (int r = 0; r < 4; ++r) {
            float xv = Xs[(rb + r) * 513 + k];
            a1[r] += xv * w1;
            a2[r] += xv * w2;
        }
    }
    #pragma unroll
    for (int r = 0; r < 4; ++r) {
        int i = i0 + rb + r;
        Y [(b * NN + i) * WN + c] = a1[r];
        Xp[(b * NN + i) * WN + c] = a2[r];
    }
}

// ---------------------------------------------------------------- K2:
// h = relu(A @ Y); writes node_emb[...,:128]; zeroes agg half.
__global__ __launch_bounds__(256) void k2_gcn_node(
    const float* __restrict__ adj, const int* __restrict__ num_obj,
    const float* __restrict__ Y, float* __restrict__ node_emb)
{
    __shared__ float As[16 * 129];
    int b  = blockIdx.x >> 4;
    int i0 = ((blockIdx.x >> 1) & 7) * 16;
    int ch = blockIdx.x & 1;
    int s  = num_obj[b];
    int t  = threadIdx.x;
    if (t < 128) {
        for (int rr = 0; rr < 16; ++rr) {
            int i = i0 + rr;
            float v = 0.f;
            if (i < s) {
                v = adj[(size_t)(b * NN + i) * NN + t] * ((t < s) ? 1.f : 0.f);
                if (t == i) v += 1.f;
            }
            As[rr * 129 + t] = v;
        }
    }
    __syncthreads();
    int c  = ch * 64 + (t & 63);
    int rb = (t >> 6) * 4;
    float acc[4] = {0.f,0.f,0.f,0.f};
    for (int j = 0; j < NN; ++j) {
        float yv = Y[(b * NN + j) * WN + c];
        #pragma unroll
        for (int r = 0; r < 4; ++r) acc[r] += As[(rb + r) * 129 + j] * yv;
    }
    #pragma unroll
    for (int r = 0; r < 4; ++r) {
        int i = i0 + rb + r;
        node_emb[(b * NN + i) * 256 + c]       = fmaxf(acc[r], 0.f);
        node_emb[(b * NN + i) * 256 + 128 + c] = 0.f;
    }
}

// ---------------------------------------------------------------- K3:
// G1 = (Eg * emask) @ We
__global__ __launch_bounds__(256) void k3_edge_proj(
    const float* __restrict__ ef, const float* __restrict__ We,
    const int* __restrict__ eidx, const int* __restrict__ num_edges,
    float* __restrict__ G1)
{
    __shared__ float Es[16 * 257];
    int b  = blockIdx.x >> 6;
    int m0 = (blockIdx.x & 63) * 16;
    int se = num_edges[b];
    int t  = threadIdx.x;
    for (int rr = 0; rr < 16; ++rr) {
        int m = m0 + rr;
        float v = 0.f;
        if (m < se) {
            int src = eidx[b * 2 * MM + m];
            int dst = eidx[b * 2 * MM + MM + m];
            v = ef[((size_t)(b * NN + src) * NN + dst) * DE + t];
        }
        Es[rr * 257 + t] = v;
    }
    __syncthreads();
    int c  = t & 127;
    int rb = (t >> 7) * 8;
    float acc[8];
    #pragma unroll
    for (int r = 0; r < 8; ++r) acc[r] = 0.f;
    for (int k = 0; k < DE; ++k) {
        float wv = We[k * WE + c];
        #pragma unroll
        for (int r = 0; r < 8; ++r) acc[r] += Es[(rb + r) * 257 + k] * wv;
    }
    #pragma unroll
    for (int r = 0; r < 8; ++r)
        G1[(size_t)(b * MM + m0 + rb + r) * WE + c] = acc[r];
}

// ---------------------------------------------------------------- K4:
// g[m] = relu(G1[m] + sum_j L[m,j]*G1[j]); scatter-add into agg half.
__global__ __launch_bounds__(128) void k4_line_gcn(
    const float* __restrict__ la, const float* __restrict__ G1,
    const int* __restrict__ eidx, const int* __restrict__ num_edges,
    float* __restrict__ node_emb)
{
    int b = blockIdx.x >> 10;
    int m = blockIdx.x & 1023;
    int se = num_edges[b];
    if (m >= se) return;
    __shared__ int   cnt;
    __shared__ int   idxs[MM];
    __shared__ float vals[MM];
    int t = threadIdx.x;
    if (t == 0) cnt = 0;
    __syncthreads();
    const float* larow = la + ((size_t)b * MM + m) * MM;
    for (int it = 0; it < 8; ++it) {
        int j = it * 128 + t;
        float v = larow[j];
        if (v != 0.f) {
            int pos = atomicAdd(&cnt, 1);
            idxs[pos] = j;
            vals[pos] = v;
        }
    }
    __syncthreads();
    int n = cnt;
    const float* g1b = G1 + (size_t)b * MM * WE;
    float acc = g1b[m * WE + t];
    for (int p = 0; p < n; ++p)
        acc += vals[p] * g1b[idxs[p] * WE + t];
    float g = fmaxf(acc, 0.f);
    int src = eidx[b * 2 * MM + m];
    atomicAdd(&node_emb[(b * NN + src) * 256 + 128 + t], g);
}

// ---------------------------------------------------------------- K5a:
// ci (bf16) = [emb0+emb1 (256) | relu(Xp0+Xp1) (128) | relu(ef@We2) (128)]
__global__ __launch_bounds__(256) void k5a_build_ci(
    const float* __restrict__ node_emb, const float* __restrict__ Xp,
    const float* __restrict__ ef, const float* __restrict__ We2,
    const int* __restrict__ opairs, const int* __restrict__ num_obj,
    __hip_bfloat16* __restrict__ ci)
{
    __shared__ float efs[16 * 257];
    __shared__ int   pi0[16], pi1[16];
    __shared__ float nm0[16], nm1[16];
    int b     = blockIdx.x >> 5;
    int pbase = (blockIdx.x & 31) * 16;
    int t     = threadIdx.x;
    int s     = num_obj[b];
    if (t < 16) {
        int p  = pbase + t;
        int i0 = opairs[(b * PP + p) * 2];
        int i1 = opairs[(b * PP + p) * 2 + 1];
        pi0[t] = i0; pi1[t] = i1;
        nm0[t] = (i0 < s) ? 1.f : 0.f;
        nm1[t] = (i1 < s) ? 1.f : 0.f;
    }
    __syncthreads();
    for (int pp = 0; pp < 16; ++pp) {
        int i0 = pi0[pp], i1 = pi1[pp];
        int p  = pbase + pp;
        __hip_bfloat16* cirow = ci + (size_t)(b * PP + p) * CIW;
        efs[pp * 257 + t] = ef[((size_t)(b * NN + i0) * NN + i1) * DE + t];
        float m0f = (t < 128) ? 1.f : nm0[pp];
        float m1f = (t < 128) ? 1.f : nm1[pp];
        float v = node_emb[(b * NN + i0) * 256 + t] * m0f
                + node_emb[(b * NN + i1) * 256 + t] * m1f;
        cirow[t] = __float2bfloat16(v);
        if (t < 128) {
            float pm = Xp[(b * NN + i0) * WN + t] + Xp[(b * NN + i1) * WN + t];
            cirow[256 + t] = __float2bfloat16(fmaxf(pm, 0.f));
        }
    }
    __syncthreads();
    int c   = t & 127;
    int ppb = (t >> 7) * 8;
    float acc[8];
    #pragma unroll
    for (int r = 0; r < 8; ++r) acc[r] = 0.f;
    for (int k = 0; k < DE; ++k) {
        float wv = We2[k * WE + c];
        #pragma unroll
        for (int r = 0; r < 8; ++r) acc[r] += efs[(ppb + r) * 257 + k] * wv;
    }
    #pragma unroll
    for (int r = 0; r < 8; ++r) {
        int p = pbase + ppb + r;
        ci[(size_t)(b * PP + p) * CIW + 384 + c] = __float2bfloat16(fmaxf(acc[r], 0.f));
    }
}

// ---------------------------------------------------------------- K6:
// hid(bf16) = relu(ci @ W1cat + b1cat), (8192x512)@(512x768), bf16 MFMA.
// 128x128 tile, 4 waves (2x2), each wave 4x4 grid of 16x16x32 MFMAs.
__global__ __launch_bounds__(256) void k6_mlp1_mfma(
    const ushort* __restrict__ A,   // ci  [8192][512] bf16
    const ushort* __restrict__ Bt,  // W1t [768][512] bf16 (N-major)
    const float* __restrict__ b1cat,
    __hip_bfloat16* __restrict__ H) // hid [8192][768] bf16
{
    __shared__ ushort As[128 * 32];
    __shared__ ushort Bs[128 * 32];
    int t    = threadIdx.x;
    int col0 = blockIdx.x * 128;
    int row0 = blockIdx.y * 128;
    int lane = t & 63;
    int w    = t >> 6;
    int wr   = w >> 1, wc = w & 1;
    int arow = w * 32 + (lane >> 2);   // staging row (this lane covers arow, arow+16)
    int ak   = (lane & 3) * 8;         // staging k-element offset (8 bf16 = 16B)
    int qk   = (lane >> 4) * 8;        // frag k-offset: quad*8
    int fr   = lane & 15;              // frag row/col within 16
    f32x4 acc[4][4];
    #pragma unroll
    for (int i = 0; i < 4; ++i)
        #pragma unroll
        for (int j = 0; j < 4; ++j) acc[i][j] = (f32x4){0.f, 0.f, 0.f, 0.f};

    for (int k0 = 0; k0 < CIW; k0 += 32) {
        __syncthreads();
        *(s16x8*)&As[arow * 32 + ak] =
            *(const s16x8*)&A[(size_t)(row0 + arow) * CIW + k0 + ak];
        *(s16x8*)&As[(arow + 16) * 32 + ak] =
            *(const s16x8*)&A[(size_t)(row0 + arow + 16) * CIW + k0 + ak];
        *(s16x8*)&Bs[arow * 32 + ak] =
            *(const s16x8*)&Bt[(size_t)(col0 + arow) * CIW + k0 + ak];
        *(s16x8*)&Bs[(arow + 16) * 32 + ak] =
            *(const s16x8*)&Bt[(size_t)(col0 + arow + 16) * CIW + k0 + ak];
        __syncthreads();
        s16x8 af[4], bfv[4];
        #pragma unroll
        for (int mi = 0; mi < 4; ++mi)
            af[mi] = *(const s16x8*)&As[(wr * 64 + mi * 16 + fr) * 32 + qk];
        #pragma unroll
        for (int ni = 0; ni < 4; ++ni)
            bfv[ni] = *(const s16x8*)&Bs[(wc * 64 + ni * 16 + fr) * 32 + qk];
        #pragma unroll
        for (int mi = 0; mi < 4; ++mi)
            #pragma unroll
            for (int ni = 0; ni < 4; ++ni)
                acc[mi][ni] = __builtin_amdgcn_mfma_f32_16x16x32_bf16(
                    af[mi], bfv[ni], acc[mi][ni], 0, 0, 0);
    }
    int crow = (lane >> 4) * 4;
    #pragma unroll
    for (int mi = 0; mi < 4; ++mi) {
        #pragma unroll
        for (int ni = 0; ni < 4; ++ni) {
            int gc = col0 + wc * 64 + ni * 16 + fr;
            int gr = row0 + wr * 64 + mi * 16 + crow;
            float bias = b1cat[gc];
            #pragma unroll
            for (int rg = 0; rg < 4; ++rg) {
                float v = fmaxf(acc[mi][ni][rg] + bias, 0.f);
                H[(size_t)(gr + rg) * 768 + gc] = __float2bfloat16(v);
            }
        }
    }
}

// ---------------------------------------------------------------- K7:
// out = hid @ W2 + b2 for all 3 heads. 32 lanes/pair (9+6+17=32 cols).
__global__ __launch_bounds__(256) void k7_mlp2(
    const __hip_bfloat16* __restrict__ H,   // [8192][768]
    const float* __restrict__ lrW2, const float* __restrict__ lrb2,
    const float* __restrict__ scrW2, const float* __restrict__ scrb2,
    const float* __restrict__ mrW2, const float* __restrict__ mrb2,
    float* __restrict__ outp)
{
    __shared__ float w2s[32 * 257];
    int t = threadIdx.x;
    for (int o = 0; o < 32; ++o) {
        float v;
        if (o < 9)       v = lrW2[t * 9 + o];
        else if (o < 15) v = scrW2[t * 6 + (o - 9)];
        else             v = mrW2[t * 17 + (o - 15)];
        w2s[o * 257 + t] = v;
    }
    __syncthreads();
    int p = blockIdx.x * 8 + (t >> 5);
    int o = t & 31;
    int seg = (o < 9) ? 0 : ((o < 15) ? 1 : 2);
    const ushort* hr = (const ushort*)H + (size_t)p * 768 + seg * 256;
    const float* wr = &w2s[o * 257];
    float acc = (o < 9) ? lrb2[o] : ((o < 15) ? scrb2[o - 9] : mrb2[o - 15]);
    for (int k = 0; k < HIDW; k += 2) {
        ushort2 u = *(const ushort2*)&hr[k];
        acc += bf2f(u.x) * wr[k] + bf2f(u.y) * wr[k + 1];
    }
    if (o < 9)       outp[(size_t)p * 9 + o] = acc;
    else if (o < 15) outp[8192 * 9 + (size_t)p * 6 + (o - 9)] = acc;
    else             outp[8192 * 15 + (size_t)p * 17 + (o - 15)] = acc;
}

// ----------------------------------------------------------------
extern "C" void kernel_launch(void* const* d_in, const int* in_sizes, int n_in,
                              void* d_out, int out_size, void* d_ws, size_t ws_size,
                              hipStream_t stream) {
    const float* nf    = (const float*)d_in[0];
    const float* ef    = (const float*)d_in[1];
    const float* adj   = (const float*)d_in[2];
    const float* la    = (const float*)d_in[3];
    const int*   eidx  = (const int*)d_in[4];
    const int*   opair = (const int*)d_in[5];
    const int*   nobj  = (const int*)d_in[6];
    const int*   nedg  = (const int*)d_in[7];
    const float* Wn    = (const float*)d_in[8];
    const float* We    = (const float*)d_in[9];
    const float* Wn2   = (const float*)d_in[10];
    const float* We2   = (const float*)d_in[11];
    const float* scrW1 = (const float*)d_in[12];
    const float* scrb1 = (const float*)d_in[13];
    const float* scrW2 = (const float*)d_in[14];
    const float* scrb2 = (const float*)d_in[15];
    const float* lrW1  = (const float*)d_in[16];
    const float* lrb1  = (const float*)d_in[17];
    const float* lrW2  = (const float*)d_in[18];
    const float* lrb2  = (const float*)d_in[19];
    const float* mrW1  = (const float*)d_in[20];
    const float* mrb1  = (const float*)d_in[21];
    const float* mrW2  = (const float*)d_in[22];
    const float* mrb2  = (const float*)d_in[23];

    float* ws = (float*)d_ws;
    float* Y        = ws;                    // 262144
    float* Xp       = Y + 262144;            // 262144
    float* node_emb = Xp + 262144;           // 524288
    float* G1       = node_emb + 524288;     // 2097152
    __hip_bfloat16* ci  = (__hip_bfloat16*)(G1 + 2097152);      // 8192*512 bf16
    __hip_bfloat16* hid = (__hip_bfloat16*)(G1 + 2097152 + 2097152); // 8192*768 bf16
    __hip_bfloat16* W1t = (__hip_bfloat16*)(G1 + 2097152 + 2097152 + 3145728);
    float* b1cat    = (float*)(W1t) + 196608; // 768*512 bf16 = 196608 f32 slots

    k0_prep     <<<769, 256, 0, stream>>>(lrW1, scrW1, mrW1, lrb1, scrb1, mrb1,
                                          W1t, b1cat);
    k1_node_proj<<<BB * 8 * 2, 256, 0, stream>>>(nf, Wn, Wn2, nobj, Y, Xp);
    k2_gcn_node <<<BB * 8 * 2, 256, 0, stream>>>(adj, nobj, Y, node_emb);
    k3_edge_proj<<<BB * (MM / 16), 256, 0, stream>>>(ef, We, eidx, nedg, G1);
    k4_line_gcn <<<BB * MM, 128, 0, stream>>>(la, G1, eidx, nedg, node_emb);
    k5a_build_ci<<<BB * (PP / 16), 256, 0, stream>>>(node_emb, Xp, ef, We2,
                                                     opair, nobj, ci);
    k6_mlp1_mfma<<<dim3(6, 64), 256, 0, stream>>>((const ushort*)ci,
                                                  (const ushort*)W1t, b1cat, hid);
    k7_mlp2     <<<8192 / 8, 256, 0, stream>>>(hid, lrW2, lrb2, scrW2, scrb2,
                                               mrW2, mrb2, (float*)d_out);
}

// Round 3
// 474.967 us; speedup vs baseline: 1.5970x; 1.1732x over previous
//
#include <hip/hip_runtime.h>
#include <hip/hip_bf16.h>
#include <cstdint>
#include <cstddef>

#define BB 16
#define NN 128
#define MM 1024
#define DN 512
#define DE 256
#define WN 128
#define WE 128
#define PP 512
#define HIDW 256
#define CIW 512

typedef __attribute__((ext_vector_type(8))) short s16x8;
typedef __attribute__((ext_vector_type(4))) float f32x4;

__device__ __forceinline__ float bf2f(unsigned short u) {
    unsigned int x = ((unsigned int)u) << 16;
    union { unsigned int i; float f; } c; c.i = x; return c.f;
}
__device__ __forceinline__ short f2b(float f) {
    __hip_bfloat16 h = __float2bfloat16(f);
    return *reinterpret_cast<short*>(&h);
}

// ---------------------------------------------------------------- K0:
// prep all bf16 transposed weights:
//   W1t [768][512], WncT [256][512] (=[Wn|Wn2]^T), WeT [128][256],
//   We2T [128][256], b1cat[768]
__global__ __launch_bounds__(256) void k0_prep(
    const float* __restrict__ lrW1, const float* __restrict__ scrW1,
    const float* __restrict__ mrW1,
    const float* __restrict__ lrb1, const float* __restrict__ scrb1,
    const float* __restrict__ mrb1,
    const float* __restrict__ Wn, const float* __restrict__ Wn2,
    const float* __restrict__ We, const float* __restrict__ We2,
    __hip_bfloat16* __restrict__ W1t, __hip_bfloat16* __restrict__ WncT,
    __hip_bfloat16* __restrict__ WeT, __hip_bfloat16* __restrict__ We2T,
    float* __restrict__ b1cat)
{
    int blk = blockIdx.x;
    int t = threadIdx.x;
    if (blk < 768) {
        int h = blk >> 8, n = blk & 255;
        const float* W = (h == 0) ? lrW1 : (h == 1) ? scrW1 : mrW1;
        W1t[(size_t)blk * 512 + t]       = __float2bfloat16(W[t * 256 + n]);
        W1t[(size_t)blk * 512 + t + 256] = __float2bfloat16(W[(t + 256) * 256 + n]);
    } else if (blk == 768) {
        b1cat[t]       = lrb1[t];
        b1cat[256 + t] = scrb1[t];
        b1cat[512 + t] = mrb1[t];
    } else if (blk < 897) {            // WeT rows 0..127
        int n = blk - 769;
        WeT[(size_t)n * 256 + t] = __float2bfloat16(We[t * 128 + n]);
    } else if (blk < 1153) {           // WncT rows 0..255
        int n = blk - 897;
        const float* W = (n < 128) ? Wn : Wn2;
        int c = n & 127;
        WncT[(size_t)n * 512 + t]       = __float2bfloat16(W[t * 128 + c]);
        WncT[(size_t)n * 512 + t + 256] = __float2bfloat16(W[(t + 256) * 128 + c]);
    } else {                           // We2T rows 0..127
        int n = blk - 1153;
        We2T[(size_t)n * 256 + t] = __float2bfloat16(We2[t * 128 + n]);
    }
}

// ---------------------------------------------------------------- FPROJ:
// One MFMA GEMM kernel, 3 routes (gather fused into A-staging):
//  route0 (blk   0..31 ): [Xmask]@[Wn|Wn2]  M=2048 N=256 K=512 -> Y,Xp f32
//  route1 (blk  32..159): [Eg*emask]@We     M=16384 N=128 K=256 -> G1 f32
//  route2 (blk 160..223): relu(ef_pair@We2) M=8192 N=128 K=256 -> ci[:,384:]
__global__ __launch_bounds__(256) void fproj(
    const float* __restrict__ nf, const float* __restrict__ ef,
    const int* __restrict__ eidx, const int* __restrict__ opair,
    const int* __restrict__ nobj, const int* __restrict__ nedg,
    const ushort* __restrict__ WncT, const ushort* __restrict__ WeT,
    const ushort* __restrict__ We2T,
    float* __restrict__ Y, float* __restrict__ Xp,
    float* __restrict__ G1, __hip_bfloat16* __restrict__ ci)
{
    __shared__ ushort As[128 * 32];
    __shared__ ushort Bs[128 * 32];
    __shared__ unsigned rowoff[128];
    __shared__ float    rowval[128];

    int blk = blockIdx.x;
    int route, mb, nb, K;
    const ushort* Bt;
    if (blk < 32)       { route = 0; mb = blk >> 1;  nb = blk & 1; K = 512; Bt = WncT; }
    else if (blk < 160) { route = 1; mb = blk - 32;  nb = 0;       K = 256; Bt = WeT;  }
    else                { route = 2; mb = blk - 160; nb = 0;       K = 256; Bt = We2T; }
    int row0 = mb * 128, col0 = nb * 128;
    int t = threadIdx.x;

    if (t < 128) {
        int r = row0 + t;
        unsigned off; float valid = 1.f;
        if (route == 0) {
            int b = r >> 7, i = r & 127;
            off = (unsigned)r * DN;
            valid = (i < nobj[b]) ? 1.f : 0.f;
        } else if (route == 1) {
            int b = r >> 10, m = r & 1023;
            int src = eidx[b * 2 * MM + m];
            int dst = eidx[b * 2 * MM + MM + m];
            off = (unsigned)((b * NN + src) * NN + dst) * DE;
            valid = (m < nedg[b]) ? 1.f : 0.f;
        } else {
            int r2 = r;
            int b = r2 >> 9, p = r2 & 511;
            int i0 = opair[(b * PP + p) * 2];
            int i1 = opair[(b * PP + p) * 2 + 1];
            off = (unsigned)((b * NN + i0) * NN + i1) * DE;
        }
        rowoff[t] = off; rowval[t] = valid;
    }

    const float* Asrc = (route == 0) ? nf : ef;
    int lane = t & 63;
    int w    = t >> 6;
    int wr   = w >> 1, wc = w & 1;
    int arow = w * 32 + (lane >> 2);
    int ak   = (lane & 3) * 8;
    int qk   = (lane >> 4) * 8;
    int fr   = lane & 15;
    f32x4 acc[4][4];
    #pragma unroll
    for (int i = 0; i < 4; ++i)
        #pragma unroll
        for (int j = 0; j < 4; ++j) acc[i][j] = (f32x4){0.f, 0.f, 0.f, 0.f};

    for (int k0 = 0; k0 < K; k0 += 32) {
        __syncthreads();
        {
            unsigned o0 = rowoff[arow] + k0 + ak;
            unsigned o1 = rowoff[arow + 16] + k0 + ak;
            float m0 = rowval[arow], m1 = rowval[arow + 16];
            float4 a0 = *(const float4*)&Asrc[o0];
            float4 a1 = *(const float4*)&Asrc[o0 + 4];
            float4 b0 = *(const float4*)&Asrc[o1];
            float4 b1 = *(const float4*)&Asrc[o1 + 4];
            s16x8 pa, pb;
            pa[0]=f2b(a0.x*m0); pa[1]=f2b(a0.y*m0); pa[2]=f2b(a0.z*m0); pa[3]=f2b(a0.w*m0);
            pa[4]=f2b(a1.x*m0); pa[5]=f2b(a1.y*m0); pa[6]=f2b(a1.z*m0); pa[7]=f2b(a1.w*m0);
            pb[0]=f2b(b0.x*m1); pb[1]=f2b(b0.y*m1); pb[2]=f2b(b0.z*m1); pb[3]=f2b(b0.w*m1);
            pb[4]=f2b(b1.x*m1); pb[5]=f2b(b1.y*m1); pb[6]=f2b(b1.z*m1); pb[7]=f2b(b1.w*m1);
            *(s16x8*)&As[arow * 32 + ak]        = pa;
            *(s16x8*)&As[(arow + 16) * 32 + ak] = pb;
            *(s16x8*)&Bs[arow * 32 + ak] =
                *(const s16x8*)&Bt[(size_t)(col0 + arow) * K + k0 + ak];
            *(s16x8*)&Bs[(arow + 16) * 32 + ak] =
                *(const s16x8*)&Bt[(size_t)(col0 + arow + 16) * K + k0 + ak];
        }
        __syncthreads();
        s16x8 af[4], bfv[4];
        #pragma unroll
        for (int mi = 0; mi < 4; ++mi)
            af[mi] = *(const s16x8*)&As[(wr * 64 + mi * 16 + fr) * 32 + qk];
        #pragma unroll
        for (int ni = 0; ni < 4; ++ni)
            bfv[ni] = *(const s16x8*)&Bs[(wc * 64 + ni * 16 + fr) * 32 + qk];
        #pragma unroll
        for (int mi = 0; mi < 4; ++mi)
            #pragma unroll
            for (int ni = 0; ni < 4; ++ni)
                acc[mi][ni] = __builtin_amdgcn_mfma_f32_16x16x32_bf16(
                    af[mi], bfv[ni], acc[mi][ni], 0, 0, 0);
    }
    int crow = (lane >> 4) * 4;
    #pragma unroll
    for (int mi = 0; mi < 4; ++mi) {
        #pragma unroll
        for (int ni = 0; ni < 4; ++ni) {
            int gc = col0 + wc * 64 + ni * 16 + fr;
            int gr = row0 + wr * 64 + mi * 16 + crow;
            #pragma unroll
            for (int rg = 0; rg < 4; ++rg) {
                float v = acc[mi][ni][rg];
                int r = gr + rg;
                if (route == 0) {
                    if (gc < 128) Y [(size_t)r * WN + gc]       = v;
                    else          Xp[(size_t)r * WN + gc - 128] = v;
                } else if (route == 1) {
                    G1[(size_t)r * WE + gc] = v;
                } else {
                    ci[(size_t)r * CIW + 384 + gc] = __float2bfloat16(fmaxf(v, 0.f));
                }
            }
        }
    }
}

// ---------------------------------------------------------------- K2:
// h = relu(A @ Y); writes node_emb[...,:128]; zeroes agg half.
__global__ __launch_bounds__(256) void k2_gcn_node(
    const float* __restrict__ adj, const int* __restrict__ num_obj,
    const float* __restrict__ Y, float* __restrict__ node_emb)
{
    __shared__ float As[16 * 129];
    int b  = blockIdx.x >> 4;
    int i0 = ((blockIdx.x >> 1) & 7) * 16;
    int ch = blockIdx.x & 1;
    int s  = num_obj[b];
    int t  = threadIdx.x;
    if (t < 128) {
        for (int rr = 0; rr < 16; ++rr) {
            int i = i0 + rr;
            float v = 0.f;
            if (i < s) {
                v = adj[(size_t)(b * NN + i) * NN + t] * ((t < s) ? 1.f : 0.f);
                if (t == i) v += 1.f;
            }
            As[rr * 129 + t] = v;
        }
    }
    __syncthreads();
    int c  = ch * 64 + (t & 63);
    int rb = (t >> 6) * 4;
    float acc[4] = {0.f,0.f,0.f,0.f};
    for (int j = 0; j < NN; ++j) {
        float yv = Y[(b * NN + j) * WN + c];
        #pragma unroll
        for (int r = 0; r < 4; ++r) acc[r] += As[(rb + r) * 129 + j] * yv;
    }
    #pragma unroll
    for (int r = 0; r < 4; ++r) {
        int i = i0 + rb + r;
        node_emb[(b * NN + i) * 256 + c]       = fmaxf(acc[r], 0.f);
        node_emb[(b * NN + i) * 256 + 128 + c] = 0.f;
    }
}

// ---------------------------------------------------------------- K4:
// g[m] = relu(G1[m] + sum_j L[m,j]*G1[j]); scatter-add into agg half.
__global__ __launch_bounds__(128) void k4_line_gcn(
    const float* __restrict__ la, const float* __restrict__ G1,
    const int* __restrict__ eidx, const int* __restrict__ num_edges,
    float* __restrict__ node_emb)
{
    int b = blockIdx.x >> 10;
    int m = blockIdx.x & 1023;
    int se = num_edges[b];
    if (m >= se) return;
    __shared__ int   cnt;
    __shared__ int   idxs[MM];
    __shared__ float vals[MM];
    int t = threadIdx.x;
    if (t == 0) cnt = 0;
    __syncthreads();
    const float* larow = la + ((size_t)b * MM + m) * MM;
    for (int it = 0; it < 8; ++it) {
        int j = it * 128 + t;
        float v = larow[j];
        if (v != 0.f) {
            int pos = atomicAdd(&cnt, 1);
            idxs[pos] = j;
            vals[pos] = v;
        }
    }
    __syncthreads();
    int n = cnt;
    const float* g1b = G1 + (size_t)b * MM * WE;
    float acc = g1b[m * WE + t];
    for (int p = 0; p < n; ++p)
        acc += vals[p] * g1b[idxs[p] * WE + t];
    float g = fmaxf(acc, 0.f);
    int src = eidx[b * 2 * MM + m];
    atomicAdd(&node_emb[(b * NN + src) * 256 + 128 + t], g);
}

// ---------------------------------------------------------------- K5a:
// ci[:,0:384] (bf16) = [emb0+emb1 (256) | relu(Xp0+Xp1) (128)]
__global__ __launch_bounds__(256) void k5a_build_ci(
    const float* __restrict__ node_emb, const float* __restrict__ Xp,
    const int* __restrict__ opairs, const int* __restrict__ num_obj,
    __hip_bfloat16* __restrict__ ci)
{
    __shared__ int   pi0[16], pi1[16];
    __shared__ float nm0[16], nm1[16];
    int b     = blockIdx.x >> 5;
    int pbase = (blockIdx.x & 31) * 16;
    int t     = threadIdx.x;
    int s     = num_obj[b];
    if (t < 16) {
        int p  = pbase + t;
        int i0 = opairs[(b * PP + p) * 2];
        int i1 = opairs[(b * PP + p) * 2 + 1];
        pi0[t] = i0; pi1[t] = i1;
        nm0[t] = (i0 < s) ? 1.f : 0.f;
        nm1[t] = (i1 < s) ? 1.f : 0.f;
    }
    __syncthreads();
    for (int pp = 0; pp < 16; ++pp) {
        int i0 = pi0[pp], i1 = pi1[pp];
        int p  = pbase + pp;
        __hip_bfloat16* cirow = ci + (size_t)(b * PP + p) * CIW;
        float m0f = (t < 128) ? 1.f : nm0[pp];
        float m1f = (t < 128) ? 1.f : nm1[pp];
        float v = node_emb[(b * NN + i0) * 256 + t] * m0f
                + node_emb[(b * NN + i1) * 256 + t] * m1f;
        cirow[t] = __float2bfloat16(v);
        if (t < 128) {
            float pm = Xp[(b * NN + i0) * WN + t] + Xp[(b * NN + i1) * WN + t];
            cirow[256 + t] = __float2bfloat16(fmaxf(pm, 0.f));
        }
    }
}

// ---------------------------------------------------------------- K6:
// hid(bf16) = relu(ci @ W1cat + b1cat), (8192x512)@(512x768), bf16 MFMA.
__global__ __launch_bounds__(256) void k6_mlp1_mfma(
    const ushort* __restrict__ A,   // ci  [8192][512] bf16
    const ushort* __restrict__ Bt,  // W1t [768][512] bf16 (N-major)
    const float* __restrict__ b1cat,
    __hip_bfloat16* __restrict__ H) // hid [8192][768] bf16
{
    __shared__ ushort As[128 * 32];
    __shared__ ushort Bs[128 * 32];
    int t    = threadIdx.x;
    int col0 = blockIdx.x * 128;
    int row0 = blockIdx.y * 128;
    int lane = t & 63;
    int w    = t >> 6;
    int wr   = w >> 1, wc = w & 1;
    int arow = w * 32 + (lane >> 2);
    int ak   = (lane & 3) * 8;
    int qk   = (lane >> 4) * 8;
    int fr   = lane & 15;
    f32x4 acc[4][4];
    #pragma unroll
    for (int i = 0; i < 4; ++i)
        #pragma unroll
        for (int j = 0; j < 4; ++j) acc[i][j] = (f32x4){0.f, 0.f, 0.f, 0.f};

    for (int k0 = 0; k0 < CIW; k0 += 32) {
        __syncthreads();
        *(s16x8*)&As[arow * 32 + ak] =
            *(const s16x8*)&A[(size_t)(row0 + arow) * CIW + k0 + ak];
        *(s16x8*)&As[(arow + 16) * 32 + ak] =
            *(const s16x8*)&A[(size_t)(row0 + arow + 16) * CIW + k0 + ak];
        *(s16x8*)&Bs[arow * 32 + ak] =
            *(const s16x8*)&Bt[(size_t)(col0 + arow) * CIW + k0 + ak];
        *(s16x8*)&Bs[(arow + 16) * 32 + ak] =
            *(const s16x8*)&Bt[(size_t)(col0 + arow + 16) * CIW + k0 + ak];
        __syncthreads();
        s16x8 af[4], bfv[4];
        #pragma unroll
        for (int mi = 0; mi < 4; ++mi)
            af[mi] = *(const s16x8*)&As[(wr * 64 + mi * 16 + fr) * 32 + qk];
        #pragma unroll
        for (int ni = 0; ni < 4; ++ni)
            bfv[ni] = *(const s16x8*)&Bs[(wc * 64 + ni * 16 + fr) * 32 + qk];
        #pragma unroll
        for (int mi = 0; mi < 4; ++mi)
            #pragma unroll
            for (int ni = 0; ni < 4; ++ni)
                acc[mi][ni] = __builtin_amdgcn_mfma_f32_16x16x32_bf16(
                    af[mi], bfv[ni], acc[mi][ni], 0, 0, 0);
    }
    int crow = (lane >> 4) * 4;
    #pragma unroll
    for (int mi = 0; mi < 4; ++mi) {
        #pragma unroll
        for (int ni = 0; ni < 4; ++ni) {
            int gc = col0 + wc * 64 + ni * 16 + fr;
            int gr = row0 + wr * 64 + mi * 16 + crow;
            float bias = b1cat[gc];
            #pragma unroll
            for (int rg = 0; rg < 4; ++rg) {
                float v = fmaxf(acc[mi][ni][rg] + bias, 0.f);
                H[(size_t)(gr + rg) * 768 + gc] = __float2bfloat16(v);
            }
        }
    }
}

// ---------------------------------------------------------------- K7:
// out = hid @ W2 + b2 for all 3 heads. 32 lanes/pair (9+6+17=32 cols).
__global__ __launch_bounds__(256) void k7_mlp2(
    const __hip_bfloat16* __restrict__ H,   // [8192][768]
    const float* __restrict__ lrW2, const float* __restrict__ lrb2,
    const float* __restrict__ scrW2, const float* __restrict__ scrb2,
    const float* __restrict__ mrW2, const float* __restrict__ mrb2,
    float* __restrict__ outp)
{
    __shared__ float w2s[32 * 257];
    int t = threadIdx.x;
    for (int o = 0; o < 32; ++o) {
        float v;
        if (o < 9)       v = lrW2[t * 9 + o];
        else if (o < 15) v = scrW2[t * 6 + (o - 9)];
        else             v = mrW2[t * 17 + (o - 15)];
        w2s[o * 257 + t] = v;
    }
    __syncthreads();
    int p = blockIdx.x * 8 + (t >> 5);
    int o = t & 31;
    int seg = (o < 9) ? 0 : ((o < 15) ? 1 : 2);
    const ushort* hr = (const ushort*)H + (size_t)p * 768 + seg * 256;
    const float* wr = &w2s[o * 257];
    float acc = (o < 9) ? lrb2[o] : ((o < 15) ? scrb2[o - 9] : mrb2[o - 15]);
    for (int k = 0; k < HIDW; k += 2) {
        ushort2 u = *(const ushort2*)&hr[k];
        acc += bf2f(u.x) * wr[k] + bf2f(u.y) * wr[k + 1];
    }
    if (o < 9)       outp[(size_t)p * 9 + o] = acc;
    else if (o < 15) outp[8192 * 9 + (size_t)p * 6 + (o - 9)] = acc;
    else             outp[8192 * 15 + (size_t)p * 17 + (o - 15)] = acc;
}

// ----------------------------------------------------------------
extern "C" void kernel_launch(void* const* d_in, const int* in_sizes, int n_in,
                              void* d_out, int out_size, void* d_ws, size_t ws_size,
                              hipStream_t stream) {
    const float* nf    = (const float*)d_in[0];
    const float* ef    = (const float*)d_in[1];
    const float* adj   = (const float*)d_in[2];
    const float* la    = (const float*)d_in[3];
    const int*   eidx  = (const int*)d_in[4];
    const int*   opair = (const int*)d_in[5];
    const int*   nobj  = (const int*)d_in[6];
    const int*   nedg  = (const int*)d_in[7];
    const float* Wn    = (const float*)d_in[8];
    const float* We    = (const float*)d_in[9];
    const float* Wn2   = (const float*)d_in[10];
    const float* We2   = (const float*)d_in[11];
    const float* scrW1 = (const float*)d_in[12];
    const float* scrb1 = (const float*)d_in[13];
    const float* scrW2 = (const float*)d_in[14];
    const float* scrb2 = (const float*)d_in[15];
    const float* lrW1  = (const float*)d_in[16];
    const float* lrb1  = (const float*)d_in[17];
    const float* lrW2  = (const float*)d_in[18];
    const float* lrb2  = (const float*)d_in[19];
    const float* mrW1  = (const float*)d_in[20];
    const float* mrb1  = (const float*)d_in[21];
    const float* mrW2  = (const float*)d_in[22];
    const float* mrb2  = (const float*)d_in[23];

    float* ws = (float*)d_ws;
    float* Y        = ws;                    // 262144 f32
    float* Xp       = Y + 262144;            // 262144
    float* node_emb = Xp + 262144;           // 524288
    float* G1       = node_emb + 524288;     // 2097152
    float* base     = G1 + 2097152;
    __hip_bfloat16* ci   = (__hip_bfloat16*)base;            // 8192*512  = 2097152 f32 slots
    __hip_bfloat16* hid  = (__hip_bfloat16*)(base + 2097152);// 8192*768  = 3145728 f32 slots
    __hip_bfloat16* W1t  = (__hip_bfloat16*)(base + 2097152 + 3145728);   // 196608 f32
    __hip_bfloat16* WncT = (__hip_bfloat16*)(base + 2097152 + 3145728 + 196608); // 65536 f32
    __hip_bfloat16* WeT  = (__hip_bfloat16*)(base + 2097152 + 3145728 + 196608 + 65536); // 16384
    __hip_bfloat16* We2T = (__hip_bfloat16*)(base + 2097152 + 3145728 + 196608 + 65536 + 16384);
    float* b1cat = base + 2097152 + 3145728 + 196608 + 65536 + 16384 + 16384;

    k0_prep <<<1281, 256, 0, stream>>>(lrW1, scrW1, mrW1, lrb1, scrb1, mrb1,
                                       Wn, Wn2, We, We2,
                                       W1t, WncT, WeT, We2T, b1cat);
    fproj   <<<224, 256, 0, stream>>>(nf, ef, eidx, opair, nobj, nedg,
                                      (const ushort*)WncT, (const ushort*)WeT,
                                      (const ushort*)We2T, Y, Xp, G1, ci);
    k2_gcn_node <<<BB * 8 * 2, 256, 0, stream>>>(adj, nobj, Y, node_emb);
    k4_line_gcn <<<BB * MM, 128, 0, stream>>>(la, G1, eidx, nedg, node_emb);
    k5a_build_ci<<<BB * (PP / 16), 256, 0, stream>>>(node_emb, Xp, opair, nobj, ci);
    k6_mlp1_mfma<<<dim3(6, 64), 256, 0, stream>>>((const ushort*)ci,
                                                  (const ushort*)W1t, b1cat, hid);
    k7_mlp2     <<<8192 / 8, 256, 0, stream>>>(hid, lrW2, lrb2, scrW2, scrb2,
                                               mrW2, mrb2, (float*)d_out);
}